// Round 16
// baseline (1491.171 us; speedup 1.0000x reference)
//
#include <hip/hip_runtime.h>
#include <cstdint>

// Problem constants
#define BB 128   // batch
#define TT 256   // decode steps / T_CHAR
#define EE 512   // embed
#define NC 128   // n_chars
#define STAG 32  // T_TAG

// LSTM persistent-kernel geometry: 2D split
#define NWG 64   // = SB * SC lstm blocks
#define SB 4     // batch splits  (32 rows each)
#define SC 16    // column splits (32 h-cols / 128 gate cols each)
#define NKV 2304 // workers: 1024 charK + 1024 charV(T) + 128 tagK + 128 tagV(T)

using bf = unsigned short;  // bf16 storage
typedef __attribute__((ext_vector_type(8))) short short8;
typedef __attribute__((ext_vector_type(8))) unsigned short ushort8;
typedef __attribute__((ext_vector_type(16))) float f32x16;
typedef unsigned long long u64;

static __device__ __forceinline__ float bfu(bf x) { return __uint_as_float(((uint32_t)x) << 16); }
static __device__ __forceinline__ uint32_t f2bf(float f) {
    uint32_t u = __float_as_uint(f);
    return (u + 0x7FFFu + ((u >> 16) & 1u)) >> 16;  // RNE
}
static __device__ __forceinline__ float sigmoidf_(float x) { return 1.f / (1.f + expf(-x)); }

static __device__ __forceinline__ uint4 pack8bf(float4 a, float4 b) {
    uint4 o;
    o.x = (f2bf(a.y) << 16) | f2bf(a.x);
    o.y = (f2bf(a.w) << 16) | f2bf(a.z);
    o.z = (f2bf(b.y) << 16) | f2bf(b.x);
    o.w = (f2bf(b.w) << 16) | f2bf(b.z);
    return o;
}

// relu on two packed bf16 (clear if sign bit set)
static __device__ __forceinline__ uint32_t relu2bf(uint32_t x) {
    uint32_t lo = x & 0xFFFFu, hi = x >> 16;
    lo = (lo & 0x8000u) ? 0u : lo;
    hi = (hi & 0x8000u) ? 0u : hi;
    return lo | (hi << 16);
}

// ---------------------------------------------------------------------------
__global__ void diag_ws(float* __restrict__ out, float v, int n) {
    int i = blockIdx.x * 256 + threadIdx.x;
    if (i < n) out[i] = v;
}

// ---------------------------------------------------------------------------
// Merged prep (one dispatch): flags zero | h0_pack | bt_prep2 | x_prep(wave)
//                             | conv_w8 | conv_f2b(WoutB)
// Block ranges: [0,512) [512,768) [768,1280) [1280,2304) [2304,4352) [4352,4480)
// ---------------------------------------------------------------------------
struct W8 { const float* p[8]; };
struct PrepArgs {
    char* flags;                       // 2 MB -> zero
    const float* hn; bf* Hext;         // h0 pack (H2 layout)
    const float* Whh; bf* Btg2;        // Whh slice pack
    const float* tos; int* xidx; float* xval;
    W8 w8; bf* Wbf;                    // 8 attention weights -> bf16
    const float* outW; bf* WoutB;      // out weights -> bf16
};

__global__ __launch_bounds__(256) void prep_all(PrepArgs p) {
    const int blk = blockIdx.x, tid = threadIdx.x;
    if (blk < 512) {
        uint4 z = {0u, 0u, 0u, 0u};
        ((uint4*)p.flags)[blk * 256 + tid] = z;
    } else if (blk < 768) {
        int id = (blk - 512) * 256 + tid;              // 65536
        int b = id >> 9, e = id & 511;
        float v = (e < 256) ? p.hn[(size_t)b * 256 + e]
                            : p.hn[(size_t)(BB + b) * 256 + (e - 256)];
        p.Hext[((size_t)(e >> 3) * BB + b) * 8 + (e & 7)] = (bf)f2bf(v);
    } else if (blk < 1280) {
        int id = (blk - 768) * 256 + tid;              // 131072; 8 elems each
        int row = id >> 6, chunk = (id & 63) * 8;
        int cg = row >> 7, n = row & 127;
        int r = (n & 3) * 512 + cg * 32 + (n >> 2);
        const float* src = p.Whh + (size_t)r * 512 + chunk;
        ushort8 o;
#pragma unroll
        for (int i = 0; i < 8; ++i) o[i] = (bf)f2bf(src[i]);
        *(ushort8*)(p.Btg2 + (size_t)row * 512 + chunk) = o;
    } else if (blk < 2304) {
        // wave-parallel one-hot extraction: one wave per (t,b) row, 8 rows/wave
        int wgl = (blk - 1280) * 4 + (tid >> 6);       // global wave id 0..4095
        int l = tid & 63;
        for (int r = 0; r < 8; ++r) {
            int row = wgl * 8 + r;                     // 0..32767
            int t = row >> 7, b = row & 127;
            int li = 0; float lv = 0.f;
            if (t > 0) {
                const float* src = p.tos + ((size_t)b * TT + t) * NC;
                float v0 = src[l * 2], v1 = src[l * 2 + 1];
                if (v0 != 0.f) { li = l * 2;     lv = v0; }
                if (v1 != 0.f) { li = l * 2 + 1; lv = v1; }
#pragma unroll
                for (int d = 1; d < 64; d <<= 1) {
                    li += __shfl_xor(li, d);
                    lv += __shfl_xor(lv, d);
                }
            }
            if (l == 0) {
                p.xidx[(size_t)t * BB + b] = li;
                p.xval[(size_t)t * BB + b] = lv;
            }
        }
    } else if (blk < 4352) {
        int idx = blk - 2304;                          // 2048 blocks
        int m = idx >> 8;
        int i = ((idx & 255) * 256 + tid) * 4;
        float4 v = *(const float4*)(p.w8.p[m] + i);
        ushort4 o = { (bf)f2bf(v.x), (bf)f2bf(v.y), (bf)f2bf(v.z), (bf)f2bf(v.w) };
        *(ushort4*)(p.Wbf + (size_t)m * 262144 + i) = o;
    } else {
        int i = ((blk - 4352) * 256 + tid) * 4;        // 131072 elems
        float4 v = *(const float4*)(p.outW + i);
        ushort4 o = { (bf)f2bf(v.x), (bf)f2bf(v.y), (bf)f2bf(v.z), (bf)f2bf(v.w) };
        *(ushort4*)(p.WoutB + i) = o;
    }
}

// ---------------------------------------------------------------------------
// shared LDS offset swizzle for the tiled worker GEMM
// ---------------------------------------------------------------------------
static __device__ __forceinline__ int lds_off(int row, int colbyte) {
    return row * 128 + (colbyte ^ ((row & 7) << 4));
}

// Worker GEMM body: C = bf16(A_f32 @ Wb^T + bias). K = 512.
// MODE 0: C[m][512] row-major.  MODE 1: V^T char  C[(b*512+n)*256+s], m=b*256+s.
// MODE 2: V^T tag  C[(b*512+n)*32+s], m=b*32+s.
template <int MODE>
static __device__ __forceinline__ void worker_gemm(
    const float* __restrict__ Af, const bf* __restrict__ Wb,
    const float* __restrict__ bias, bf* __restrict__ C,
    int bm, int bn, char* smem)
{
    bf* As = (bf*)smem;
    bf* Bs = (bf*)(smem + 16384);
    const int tid = threadIdx.x;
    const int w = tid >> 6, l = tid & 63;
    const int wr = (w >> 1) * 64, wc = (w & 1) * 64;

    f32x16 acc[2][2];
#pragma unroll
    for (int i = 0; i < 2; ++i)
#pragma unroll
        for (int j = 0; j < 2; ++j)
#pragma unroll
            for (int r = 0; r < 16; ++r) acc[i][j][r] = 0.f;

    const int srow = tid >> 3;          // 0..31
    const int scolb = (tid & 7) * 16;   // byte col
    const int scole = (tid & 7) * 8;    // elem col

    for (int k0 = 0; k0 < 512; k0 += 64) {
#pragma unroll
        for (int pass = 0; pass < 4; ++pass) {
            int row = pass * 32 + srow;
            const float* ap = Af + (size_t)(bm + row) * 512 + k0 + scole;
            float4 v0 = *(const float4*)ap;
            float4 v1 = *(const float4*)(ap + 4);
            *(uint4*)((char*)As + lds_off(row, scolb)) = pack8bf(v0, v1);
            uint4 vb = *(const uint4*)(Wb + (size_t)(bn + row) * 512 + k0 + scole);
            *(uint4*)((char*)Bs + lds_off(row, scolb)) = vb;
        }
        __syncthreads();
#pragma unroll
        for (int kt = 0; kt < 4; ++kt) {
            const int cb = kt * 32 + (l >> 5) * 16;
            short8 af[2], bfr[2];
#pragma unroll
            for (int i = 0; i < 2; ++i) {
                af[i]  = *(const short8*)((char*)As + lds_off(wr + i * 32 + (l & 31), cb));
                bfr[i] = *(const short8*)((char*)Bs + lds_off(wc + i * 32 + (l & 31), cb));
            }
#pragma unroll
            for (int i = 0; i < 2; ++i)
#pragma unroll
                for (int j = 0; j < 2; ++j)
                    acc[i][j] = __builtin_amdgcn_mfma_f32_32x32x16_bf16(af[i], bfr[j], acc[i][j], 0, 0, 0);
        }
        __syncthreads();
    }

#pragma unroll
    for (int i = 0; i < 2; ++i)
#pragma unroll
        for (int j = 0; j < 2; ++j) {
            int n = bn + wc + j * 32 + (l & 31);
            float bv = bias[n];
#pragma unroll
            for (int r = 0; r < 16; ++r) {
                int m = bm + wr + i * 32 + (r & 3) + 8 * (r >> 2) + 4 * (l >> 5);
                bf v = (bf)f2bf(acc[i][j][r] + bv);
                if constexpr (MODE == 0) {
                    C[(size_t)m * 512 + n] = v;
                } else if constexpr (MODE == 1) {
                    int b = m >> 8, s = m & 255;
                    C[((size_t)b * 512 + n) * 256 + s] = v;
                } else {
                    int b = m >> 5, s = m & 31;
                    C[((size_t)b * 512 + n) * 32 + s] = v;
                }
            }
        }
}

// ---------------------------------------------------------------------------
// Fused persistent LSTM + K/V-projection workers (V written transposed).
// (r9-identical, proven correct at absmax 0.00586.)
// ---------------------------------------------------------------------------
struct KVArgs {
    const float *Ac, *At;                  // char_enc, tag_enc (fp32)
    const bf *WcK, *WcV, *WtK, *WtV;       // bf16 weights
    const float *bcK, *bcV, *btK, *btV;    // biases
    bf *Kc, *VcT, *Kt, *VtT;               // outputs (V transposed [b][e][s])
};

__global__ __launch_bounds__(256, 1) void lstm_fused(
    bf* __restrict__ Hext,           // H2: [TT+1][64][BB][8]; [0] prefilled
    const bf* __restrict__ Btg2,     // [SC*128][512]
    const float* __restrict__ Wih,   // [2048][128]
    const float* __restrict__ bih, const float* __restrict__ bhh,
    const float* __restrict__ cn,    // [2][128][256]
    const int* __restrict__ xidx, const float* __restrict__ xval,
    char* __restrict__ flags,        // [TT][SB][16*128B], zeroed
    KVArgs kv)
{
    __shared__ __align__(16) char smem[66048];

    const int gb = blockIdx.x, tid = threadIdx.x;

    if (gb >= NWG) {
        // ---------------- worker path ----------------
        int w = gb - NWG;
        if (w < 1024) {
            worker_gemm<0>(kv.Ac, kv.WcK, kv.bcK, kv.Kc, (w >> 2) * 128, (w & 3) * 128, smem);
        } else if (w < 2048) {
            int t = w - 1024;
            worker_gemm<1>(kv.Ac, kv.WcV, kv.bcV, kv.VcT, (t >> 2) * 128, (t & 3) * 128, smem);
        } else if (w < 2176) {
            int t = w - 2048;
            worker_gemm<0>(kv.At, kv.WtK, kv.btK, kv.Kt, (t >> 2) * 128, (t & 3) * 128, smem);
        } else {
            int t = w - 2176;
            worker_gemm<2>(kv.At, kv.WtV, kv.btV, kv.VtT, (t >> 2) * 128, (t & 3) * 128, smem);
        }
        return;
    }

    // ---------------- LSTM path ----------------
    bf*    Alds   = (bf*)smem;                    // 32 KB (frag layout)
    float* gatesf = (float*)smem;                 // overlay: [32][132] fp32
    bf*    wihtp  = (bf*)(smem + 32768);          // [128][128]
    float* biass  = (float*)(smem + 65536);       // [128]

    const int g = gb;
    const int bh = g >> 4, cg = g & 15;

    // ---- prologue: WihT slice + bias ----
    for (int x = tid; x < 128 * NC; x += 256) {   // x = n*128 + k
        int n = x >> 7, k = x & 127;
        int r = (n & 3) * 512 + cg * 32 + (n >> 2);
        wihtp[k * 128 + n] = (bf)f2bf(Wih[(size_t)r * NC + k]);
    }
    if (tid < 128) {
        int r = (tid & 3) * 512 + cg * 32 + (tid >> 2);
        biass[tid] = bih[r] + bhh[r];
    }

    const int b_loc = tid >> 3, u = tid & 7;
    const int b_glob = bh * 32 + b_loc;
    float creg[4];
    {
        int j0 = cg * 32 + u * 4;
        const float* csrc = (cg < 8) ? (cn + (size_t)b_glob * 256 + j0)
                                     : (cn + (size_t)(BB + b_glob) * 256 + (j0 - 256));
#pragma unroll
        for (int i = 0; i < 4; ++i) creg[i] = csrc[i];
    }

    const int wv = tid >> 6, l = tid & 63;

    // B preload into registers: 32 k-steps x short8 = 128 VGPR, kept all run
    short8 breg[32];
    {
        const bf* bsrc = Btg2 + ((size_t)(cg * 128 + wv * 32 + (l & 31)) * 512)
                       + (l >> 5) * 8;
#pragma unroll
        for (int kt = 0; kt < 32; ++kt) breg[kt] = *(const short8*)(bsrc + kt * 16);
    }
    __syncthreads();

    const int sb = tid & 31, sg0 = tid >> 5;
    const int dst_lane = sb | ((sg0 & 1) << 5);
    bf* dstbase = Alds + (size_t)(sg0 >> 1) * 512 + dst_lane * 8;   // + i*2048

    u64* Hw = (u64*)Hext;
    const size_t SLABB = (size_t)BB * EE * 2;      // bytes per t-slab
    const size_t SLAB64 = (size_t)BB * EE / 4;     // u64 per t-slab
    const size_t hst_off = (size_t)(cg * 4 + (u >> 1)) * 256 + b_glob * 2 + (u & 1);
    const bf* ards = Alds + l * 8;

    for (int t = 0; t < TT; ++t) {
        // ---- stage A: 8 batched bypass dwordx4 loads -> LDS (frag layout) ----
        const char* At = (const char*)Hext + (size_t)t * SLABB
                       + (size_t)sg0 * 2048 + (size_t)(bh * 32 + sb) * 16;
        uint4 areg[8];
#pragma unroll
        for (int i = 0; i < 8; ++i) {
            asm volatile("global_load_dwordx4 %0, %1, off sc0 sc1"
                         : "=v"(areg[i]) : "v"(At + (size_t)i * 16384));
        }
        float xv = xval[(size_t)t * BB + b_glob];
        int   xi = xidx[(size_t)t * BB + b_glob];
        asm volatile("s_waitcnt vmcnt(0)" ::: "memory");
        __builtin_amdgcn_sched_barrier(0);
#pragma unroll
        for (int i = 0; i < 8; ++i)
            *(uint4*)(dstbase + (size_t)i * 2048) = areg[i];
        __syncthreads();

        // ---- gates tile: 32 rows x 32 cols per wave, K=512 ----
        f32x16 acc0, acc1;
#pragma unroll
        for (int i = 0; i < 16; ++i) { acc0[i] = 0.f; acc1[i] = 0.f; }
#pragma unroll
        for (int kt = 0; kt < 32; kt += 2) {
            short8 a0 = *(const short8*)(ards + (size_t)kt * 512);
            short8 a1 = *(const short8*)(ards + (size_t)(kt + 1) * 512);
            acc0 = __builtin_amdgcn_mfma_f32_32x32x16_bf16(a0, breg[kt], acc0, 0, 0, 0);
            acc1 = __builtin_amdgcn_mfma_f32_32x32x16_bf16(a1, breg[kt + 1], acc1, 0, 0, 0);
        }
        __syncthreads();   // Alds reads complete before gates overlay write
#pragma unroll
        for (int r = 0; r < 16; ++r) {
            int m = (r & 3) + 8 * (r >> 2) + 4 * (l >> 5);   // verified C/D map
            gatesf[m * 132 + wv * 32 + (l & 31)] = acc0[r] + acc1[r];
        }
        __syncthreads();

        // ---- nonlinearity ----
        {
            union { ushort4 v; u64 uu; } hout;
#pragma unroll
            for (int i = 0; i < 4; ++i) {
                int nb = (u * 4 + i) * 4;          // gate-col base (q=0..3)
                float4 ga  = *(const float4*)&gatesf[b_loc * 132 + nb];
                float4 bb4 = *(const float4*)&biass[nb];
                ushort4 xw = *(const ushort4*)&wihtp[xi * 128 + nb];
                float a0 = ga.x + bb4.x + xv * bfu(xw.x);   // i
                float a1 = ga.y + bb4.y + xv * bfu(xw.y);   // f
                float a2 = ga.z + bb4.z + xv * bfu(xw.z);   // g
                float a3 = ga.w + bb4.w + xv * bfu(xw.w);   // o
                float ig = sigmoidf_(a0);
                float fg = sigmoidf_(a1);
                float gg = tanhf(a2);
                float og = sigmoidf_(a3);
                creg[i] = fg * creg[i] + ig * gg;
                float hnew = og * tanhf(creg[i]);
                hout.v[i] = (bf)f2bf(hnew);
            }
            __hip_atomic_store(Hw + (size_t)(t + 1) * SLAB64 + hst_off, hout.uu,
                               __ATOMIC_RELAXED, __HIP_MEMORY_SCOPE_AGENT);
        }

        if (t + 1 < TT) {
            asm volatile("s_waitcnt vmcnt(0)" ::: "memory");   // h stores drained
            __syncthreads();
            char* fb = flags + (size_t)(t + 1) * (SB * 2048) + (size_t)bh * 2048;
            if (tid == 0)
                __hip_atomic_store((int*)(fb + (size_t)cg * 128), 1,
                                   __ATOMIC_RELAXED, __HIP_MEMORY_SCOPE_SYSTEM);
            if (tid < 64) {
                const int* fp = (const int*)(fb + (size_t)(tid & 15) * 128);
                while (true) {
                    int v = __hip_atomic_load(fp, __ATOMIC_RELAXED,
                                              __HIP_MEMORY_SCOPE_SYSTEM);
                    if (__all(v != 0)) break;
                    __builtin_amdgcn_s_sleep(1);
                }
            }
            asm volatile("" ::: "memory");
            __syncthreads();
        }
    }
}

// ---------------------------------------------------------------------------
// Merged fused MFMA attention (both sides, one dispatch), overlay LDS 66.5KB
// -> 2 blocks/CU. Per (b, 32-t tile): Hstage + Qproj + QK^T + softmax + PV + Wo.
// Grid order: b varies fastest (128 = 0 mod 8 XCDs) -> all t0 tiles of a given
// b pin to the same XCD; K[b]/V[b] stay L2-resident across the 8 tiles.
// Region overlay (verified hazard-free):
//   L = [0,33280): Qs (Q, later ctx); Ps aliases L (written after Q dead)
//   U = [33280,66560): Hs (H stage, dead after ph1); scs (scores) overwrites
//       it in ph2; occs aliases U after scs dead.
// ---------------------------------------------------------------------------
template <int S>
static __device__ void attn_side(
    const bf* __restrict__ Hext,    // H2 base; slab t+1 = h_t
    const bf* __restrict__ Wq, const float* __restrict__ bq,
    const bf* __restrict__ Km,      // [BB*S][512]
    const bf* __restrict__ VT,      // [BB][512][S]
    const bf* __restrict__ Wo, const float* __restrict__ bo,
    bf* __restrict__ occ,           // [TT*BB][512]
    int t0, int b, int tid, char* smem)
{
    constexpr int SP = S + 4;     // scs pad (fp32 elems)
    constexpr int PP = S + 8;     // Ps pad (bf elems)
    bf*    Qs   = (bf*)smem;                    // [32][520]
    float* scs  = (float*)(smem + 33280);       // [32][SP]
    bf*    Ps   = (bf*)smem;                    // aliases Qs
    bf*    occs = (bf*)(smem + 33280);          // aliases scs
    char*  Hs   = smem + 33280;                 // H stage (dead before scs)

    const float QSCALE = 0.044194173824159216f;
    const int wv = tid >> 6, l = tid & 63;
    const int lm = l & 31, lh = l >> 5;

    // ---- ph0: stage H tile (t0+1..t0+32, 64 grps) for batch b -> LDS ----
    // Hs layout: [tl][grp^(tl&7)] 16B chunks (XOR spreads banks; <=4-way)
    for (int x = tid; x < 2048; x += 256) {
        int tl = x >> 6, grp = x & 63;
        uint4 v = *(const uint4*)(Hext + (((size_t)(t0 + tl + 1) * 64 + grp) * BB + b) * 8);
        *(uint4*)(Hs + tl * 1024 + ((grp ^ (tl & 7)) << 4)) = v;
    }
    __syncthreads();

    // ---- ph1: Q = (h @ Wq^T + bq)*QSCALE  (A-frags from LDS, 4x dedupe) ----
    {
        f32x16 qa[4];
#pragma unroll
        for (int nt = 0; nt < 4; ++nt)
#pragma unroll
            for (int r = 0; r < 16; ++r) qa[nt][r] = 0.f;
#pragma unroll 4
        for (int kt = 0; kt < 32; ++kt) {
            short8 a = *(const short8*)(Hs + lm * 1024 + (((kt * 2 + lh) ^ (lm & 7)) << 4));
#pragma unroll
            for (int nt = 0; nt < 4; ++nt) {
                int n = wv * 128 + nt * 32 + lm;
                short8 w = *(const short8*)(Wq + (size_t)n * 512 + kt * 16 + lh * 8);
                qa[nt] = __builtin_amdgcn_mfma_f32_32x32x16_bf16(a, w, qa[nt], 0, 0, 0);
            }
        }
#pragma unroll
        for (int nt = 0; nt < 4; ++nt) {
            int n = wv * 128 + nt * 32 + lm;
            float bv = bq[n];
#pragma unroll
            for (int r = 0; r < 16; ++r) {
                int m = (r & 3) + 8 * (r >> 2) + 4 * lh;
                Qs[m * 520 + n] = (bf)f2bf((qa[nt][r] + bv) * QSCALE);
            }
        }
    }
    __syncthreads();   // H reads done; U region free for scs

    // ---- ph2: scores = Q @ K^T ----
    {
        constexpr int NJ = (S == 256) ? 2 : 1;
        f32x16 sa[NJ];
#pragma unroll
        for (int j = 0; j < NJ; ++j)
#pragma unroll
            for (int r = 0; r < 16; ++r) sa[j][r] = 0.f;
#pragma unroll 4
        for (int kt = 0; kt < 32; ++kt) {
            short8 a = *(const short8*)&Qs[lm * 520 + kt * 16 + lh * 8];
#pragma unroll
            for (int j = 0; j < NJ; ++j) {
                int s = ((S == 256) ? (wv * 64 + j * 32) : 0) + lm;
                short8 k8 = *(const short8*)(Km + ((size_t)b * S + s) * 512 + kt * 16 + lh * 8);
                sa[j] = __builtin_amdgcn_mfma_f32_32x32x16_bf16(a, k8, sa[j], 0, 0, 0);
            }
        }
#pragma unroll
        for (int j = 0; j < NJ; ++j) {
            int s = ((S == 256) ? (wv * 64 + j * 32) : 0) + lm;
#pragma unroll
            for (int r = 0; r < 16; ++r) {
                int m = (r & 3) + 8 * (r >> 2) + 4 * lh;
                scs[m * SP + s] = sa[j][r];     // S==32: waves write same values (benign)
            }
        }
    }
    __syncthreads();

    // ---- ph3: softmax (8 threads/row); P(bf16) -> Ps (aliases dead Q) ----
    {
        int r = tid >> 3, lg = tid & 7;
        float mx = -1e30f;
        for (int c = lg; c < S; c += 8) mx = fmaxf(mx, scs[r * SP + c]);
#pragma unroll
        for (int d = 1; d < 8; d <<= 1) mx = fmaxf(mx, __shfl_xor(mx, d));
        float sum = 0.f;
        for (int c = lg; c < S; c += 8) {
            float e = expf(scs[r * SP + c] - mx);
            scs[r * SP + c] = e;
            sum += e;
        }
#pragma unroll
        for (int d = 1; d < 8; d <<= 1) sum += __shfl_xor(sum, d);
        float inv = 1.f / sum;
        for (int c = lg; c < S; c += 8) Ps[r * PP + c] = (bf)f2bf(scs[r * SP + c] * inv);
    }
    __syncthreads();

    // ---- ph4: ctx = P @ V ----
    {
        f32x16 ca[4];
#pragma unroll
        for (int nt = 0; nt < 4; ++nt)
#pragma unroll
            for (int r = 0; r < 16; ++r) ca[nt][r] = 0.f;
#pragma unroll
        for (int kt = 0; kt < S / 16; ++kt) {
            short8 a = *(const short8*)&Ps[lm * PP + kt * 16 + lh * 8];
#pragma unroll
            for (int nt = 0; nt < 4; ++nt) {
                int n = wv * 128 + nt * 32 + lm;
                short8 v8 = *(const short8*)(VT + ((size_t)b * 512 + n) * S + kt * 16 + lh * 8);
                ca[nt] = __builtin_amdgcn_mfma_f32_32x32x16_bf16(a, v8, ca[nt], 0, 0, 0);
            }
        }
        __syncthreads();   // all P reads done -> safe to overwrite L region
#pragma unroll
        for (int nt = 0; nt < 4; ++nt) {
            int n = wv * 128 + nt * 32 + lm;
#pragma unroll
            for (int r = 0; r < 16; ++r) {
                int m = (r & 3) + 8 * (r >> 2) + 4 * lh;
                Qs[m * 520 + n] = (bf)f2bf(ca[nt][r]);
            }
        }
    }
    __syncthreads();

    // ---- ph5: occ = ctx @ Wo^T + bo ; stage in LDS, coalesced store ----
    {
        f32x16 oa[4];
#pragma unroll
        for (int nt = 0; nt < 4; ++nt)
#pragma unroll
            for (int r = 0; r < 16; ++r) oa[nt][r] = 0.f;
#pragma unroll 4
        for (int kt = 0; kt < 32; ++kt) {
            short8 a = *(const short8*)&Qs[lm * 520 + kt * 16 + lh * 8];
#pragma unroll
            for (int nt = 0; nt < 4; ++nt) {
                int n = wv * 128 + nt * 32 + lm;
                short8 w = *(const short8*)(Wo + (size_t)n * 512 + kt * 16 + lh * 8);
                oa[nt] = __builtin_amdgcn_mfma_f32_32x32x16_bf16(a, w, oa[nt], 0, 0, 0);
            }
        }
#pragma unroll
        for (int nt = 0; nt < 4; ++nt) {
            int n = wv * 128 + nt * 32 + lm;
            float bv = bo[n];
#pragma unroll
            for (int r = 0; r < 16; ++r) {
                int m = (r & 3) + 8 * (r >> 2) + 4 * lh;
                occs[m * 520 + n] = (bf)f2bf(oa[nt][r] + bv);
            }
        }
        __syncthreads();
        int row = tid >> 3, c0 = (tid & 7) * 64;
        const bf* src = occs + row * 520 + c0;
        bf* dst = occ + ((size_t)(t0 + row) * BB + b) * 512 + c0;
#pragma unroll
        for (int k = 0; k < 8; ++k)
            *(uint4*)(dst + k * 8) = *(const uint4*)(src + k * 8);
    }
}

struct AttnArgs {
    const bf* Hext;
    const bf *WcQ, *WcO, *WtQ, *WtO;
    const float *bcq, *bco, *btq, *bto;
    const bf *Kc, *VcT, *Kt, *VtT;
    bf *Occ, *Oct;
};

__global__ __launch_bounds__(256, 2) void attn_all(AttnArgs a) {
    __shared__ __align__(16) char smem[66560];
    // b fastest (XCD pinning: 128 % 8 == 0 -> XCD = b % 8 for all t0/z)
    const int b = blockIdx.x, t0 = blockIdx.y * 32, tid = threadIdx.x;
    if (blockIdx.z == 0)
        attn_side<256>(a.Hext, a.WcQ, a.bcq, a.Kc, a.VcT, a.WcO, a.bco, a.Occ,
                       t0, b, tid, smem);
    else
        attn_side<32>(a.Hext, a.WtQ, a.btq, a.Kt, a.VtT, a.WtO, a.bto, a.Oct,
                      t0, b, tid, smem);
}

// ---------------------------------------------------------------------------
// Output projection (MFMA): out[b][t][:] = relu(Occ[m]) @ Wo[:, :512]^T
//   + relu(Oct[m]) @ Wo[:, 512:]^T + bias,  m = t*BB + b. N = 128.
// ---------------------------------------------------------------------------
__global__ __launch_bounds__(256) void gemm_out(
    const bf* __restrict__ A1, const bf* __restrict__ A2,
    const bf* __restrict__ Wo,      // [128][1024] bf16
    const float* __restrict__ bias, float* __restrict__ out)
{
    __shared__ __align__(16) bf As[128 * 64];
    __shared__ __align__(16) bf Bs[128 * 64];
    const int tid = threadIdx.x;
    const int bm = blockIdx.x * 128;
    const int w = tid >> 6, l = tid & 63;
    const int wr = (w >> 1) * 64, wc = (w & 1) * 64;

    f32x16 acc[2][2];
#pragma unroll
    for (int i = 0; i < 2; ++i)
#pragma unroll
        for (int j = 0; j < 2; ++j)
#pragma unroll
            for (int r = 0; r < 16; ++r) acc[i][j][r] = 0.f;

    const int srow = tid >> 3;
    const int scolb = (tid & 7) * 16;
    const int scole = (tid & 7) * 8;

    for (int k0 = 0; k0 < 1024; k0 += 64) {
        const bf* Asrc = (k0 < 512) ? A1 : A2;
        const int kk = k0 & 511;
#pragma unroll
        for (int pass = 0; pass < 4; ++pass) {
            int row = pass * 32 + srow;
            uint4 va = *(const uint4*)(Asrc + (size_t)(bm + row) * 512 + kk + scole);
            va.x = relu2bf(va.x); va.y = relu2bf(va.y);
            va.z = relu2bf(va.z); va.w = relu2bf(va.w);
            *(uint4*)((char*)As + lds_off(row, scolb)) = va;
            uint4 vb = *(const uint4*)(Wo + (size_t)row * 1024 + k0 + scole);
            *(uint4*)((char*)Bs + lds_off(row, scolb)) = vb;
        }
        __syncthreads();
#pragma unroll
        for (int kt = 0; kt < 4; ++kt) {
            const int cb = kt * 32 + (l >> 5) * 16;
            short8 af[2], bfr[2];
#pragma unroll
            for (int i = 0; i < 2; ++i) {
                af[i]  = *(const short8*)((char*)As + lds_off(wr + i * 32 + (l & 31), cb));
                bfr[i] = *(const short8*)((char*)Bs + lds_off(wc + i * 32 + (l & 31), cb));
            }
#pragma unroll
            for (int i = 0; i < 2; ++i)
#pragma unroll
                for (int j = 0; j < 2; ++j)
                    acc[i][j] = __builtin_amdgcn_mfma_f32_32x32x16_bf16(af[i], bfr[j], acc[i][j], 0, 0, 0);
        }
        __syncthreads();
    }

    // epilogue: remap rows (t,b)->(b,t), fp32 store
#pragma unroll
    for (int i = 0; i < 2; ++i)
#pragma unroll
        for (int j = 0; j < 2; ++j) {
            int n = wc + j * 32 + (l & 31);
            float bv = bias[n];
#pragma unroll
            for (int r = 0; r < 16; ++r) {
                int m = bm + wr + i * 32 + (r & 3) + 8 * (r >> 2) + 4 * (l >> 5);
                int tt = m >> 7, bb_ = m & 127;
                out[((size_t)bb_ * TT + tt) * NC + n] = acc[i][j][r] + bv;
            }
        }
}

// ---------------------------------------------------------------------------
extern "C" void kernel_launch(void* const* d_in, const int* in_sizes, int n_in,
                              void* d_out, int out_size, void* d_ws, size_t ws_size,
                              hipStream_t stream) {
    const float* char_enc = (const float*)d_in[0];
    const float* char_hn  = (const float*)d_in[1];
    const float* char_cn  = (const float*)d_in[2];
    const float* tag_enc  = (const float*)d_in[3];
    const float* tos      = (const float*)d_in[4];
    const float* Wih = (const float*)d_in[5];
    const float* Whh = (const float*)d_in[6];
    const float* bih = (const float*)d_in[7];
    const float* bhh = (const float*)d_in[8];
    const float* caWq = (const float*)d_in[9],  *caWk = (const float*)d_in[10], *caWv = (const float*)d_in[11];
    const float* cabq = (const float*)d_in[12], *cabk = (const float*)d_in[13], *cabv = (const float*)d_in[14];
    const float* caWo = (const float*)d_in[15], *cabo = (const float*)d_in[16];
    const float* taWq = (const float*)d_in[17], *taWk = (const float*)d_in[18], *taWv = (const float*)d_in[19];
    const float* tabq = (const float*)d_in[20], *tabk = (const float*)d_in[21], *tabv = (const float*)d_in[22];
    const float* taWo = (const float*)d_in[23], *tabo = (const float*)d_in[24];
    const float* outW = (const float*)d_in[25], *outb = (const float*)d_in[26];
    float* out = (float*)d_out;

    const size_t SZ  = (size_t)TT * BB * EE;       // 16,777,216 elements
    const size_t SZT = (size_t)BB * STAG * EE;     //  2,097,152 elements
    const size_t SLAB = (size_t)BB * EE;           // one t-slab of H2
    const size_t HEXT = SZ + SLAB;                 // (TT+1) slabs
    const size_t FLAGB = (size_t)TT * SB * 2048;   // 2 MB: per-step group flags

    const size_t NEED = FLAGB + HEXT * 2 + 4 * SZ * 2 + 2 * SZT * 2
                      + (size_t)SC * 128 * EE * 2 + (size_t)TT * BB * 8
                      + (8 * 262144 + 131072) * 2;
    if (ws_size < NEED) {
        diag_ws<<<dim3((out_size + 255) / 256), dim3(256), 0, stream>>>(
            out, (float)((double)ws_size / 1048576.0), out_size);
        return;
    }

    char* w = (char*)d_ws;
    char* flags = w;             w += FLAGB;
    bf* Hext = (bf*)w;           w += HEXT * 2;    // H2 layout
    bf* Kc = (bf*)w;             w += SZ * 2;      // K char [b*256+s][512]
    bf* VcT = (bf*)w;            w += SZ * 2;      // V char transposed [b][512][256]
    bf* Occ = (bf*)w;            w += SZ * 2;      // occ output of attn_c
    bf* Oct = (bf*)w;            w += SZ * 2;      // oct output of attn_t
    bf* Kt = (bf*)w;             w += SZT * 2;
    bf* VtT = (bf*)w;            w += SZT * 2;     // [b][512][32]
    bf* Btg2 = (bf*)w;           w += (size_t)SC * 128 * EE * 2;
    int* xidx = (int*)w;         w += (size_t)TT * BB * 4;
    float* xval = (float*)w;     w += (size_t)TT * BB * 4;
    bf* Wbf = (bf*)w;            w += 8 * 262144 * 2;
    bf* WoutB = (bf*)w;          w += 131072 * 2;

    bf* WbcaK = Wbf + 0 * 262144; bf* WbcaV = Wbf + 1 * 262144;
    bf* WbcaQ = Wbf + 2 * 262144; bf* WbcaO = Wbf + 3 * 262144;
    bf* WbtaK = Wbf + 4 * 262144; bf* WbtaV = Wbf + 5 * 262144;
    bf* WbtaQ = Wbf + 6 * 262144; bf* WbtaO = Wbf + 7 * 262144;

    // ---- merged prep (one dispatch) ----
    PrepArgs pp;
    pp.flags = flags;
    pp.hn = char_hn; pp.Hext = Hext;
    pp.Whh = Whh; pp.Btg2 = Btg2;
    pp.tos = tos; pp.xidx = xidx; pp.xval = xval;
    pp.w8.p[0] = caWk; pp.w8.p[1] = caWv; pp.w8.p[2] = caWq; pp.w8.p[3] = caWo;
    pp.w8.p[4] = taWk; pp.w8.p[5] = taWv; pp.w8.p[6] = taWq; pp.w8.p[7] = taWo;
    pp.Wbf = Wbf;
    pp.outW = outW; pp.WoutB = WoutB;
    prep_all<<<dim3(4480), dim3(256), 0, stream>>>(pp);

    // ---- fused: persistent LSTM + K/V projection workers (V transposed) ----
    KVArgs kv;
    kv.Ac = char_enc; kv.At = tag_enc;
    kv.WcK = WbcaK; kv.WcV = WbcaV; kv.WtK = WbtaK; kv.WtV = WbtaV;
    kv.bcK = cabk; kv.bcV = cabv; kv.btK = tabk; kv.btV = tabv;
    kv.Kc = Kc; kv.VcT = VcT; kv.Kt = Kt; kv.VtT = VtT;
    lstm_fused<<<dim3(NWG + NKV), dim3(256), 0, stream>>>(
        Hext, Btg2, Wih, bih, bhh, char_cn, xidx, xval, flags, kv);

    // ---- merged fused MFMA attention (b-fastest grid for XCD pinning) ----
    AttnArgs aa;
    aa.Hext = Hext;
    aa.WcQ = WbcaQ; aa.WcO = WbcaO; aa.WtQ = WbtaQ; aa.WtO = WbtaO;
    aa.bcq = cabq; aa.bco = cabo; aa.btq = tabq; aa.bto = tabo;
    aa.Kc = Kc; aa.VcT = VcT; aa.Kt = Kt; aa.VtT = VtT;
    aa.Occ = Occ; aa.Oct = Oct;
    attn_all<<<dim3(BB, TT / 32, 2), dim3(256), 0, stream>>>(aa);

    // ---- output projection (MFMA, fused both halves + relu + remap) ----
    gemm_out<<<dim3(256), dim3(256), 0, stream>>>(Occ, Oct, WoutB, outb, out);
}

// Round 17
// 1471.963 us; speedup vs baseline: 1.0130x; 1.0130x over previous
//
#include <hip/hip_runtime.h>
#include <cstdint>

// Problem constants
#define BB 128   // batch
#define TT 256   // decode steps / T_CHAR
#define EE 512   // embed
#define NC 128   // n_chars
#define STAG 32  // T_TAG

// LSTM persistent-kernel geometry: 2D split
#define NWG 64   // = SB * SC lstm blocks
#define SB 4     // batch splits  (32 rows each)
#define SC 16    // column splits (32 h-cols / 128 gate cols each)
#define NKV 2304 // workers: 1024 charK + 1024 charV(T) + 128 tagK + 128 tagV(T)

using bf = unsigned short;  // bf16 storage
typedef __attribute__((ext_vector_type(8))) short short8;
typedef __attribute__((ext_vector_type(8))) unsigned short ushort8;
typedef __attribute__((ext_vector_type(16))) float f32x16;
typedef unsigned long long u64;

static __device__ __forceinline__ float bfu(bf x) { return __uint_as_float(((uint32_t)x) << 16); }
static __device__ __forceinline__ uint32_t f2bf(float f) {
    uint32_t u = __float_as_uint(f);
    return (u + 0x7FFFu + ((u >> 16) & 1u)) >> 16;  // RNE
}
static __device__ __forceinline__ float sigmoidf_(float x) { return 1.f / (1.f + expf(-x)); }

static __device__ __forceinline__ uint4 pack8bf(float4 a, float4 b) {
    uint4 o;
    o.x = (f2bf(a.y) << 16) | f2bf(a.x);
    o.y = (f2bf(a.w) << 16) | f2bf(a.z);
    o.z = (f2bf(b.y) << 16) | f2bf(b.x);
    o.w = (f2bf(b.w) << 16) | f2bf(b.z);
    return o;
}

// relu on two packed bf16 (clear if sign bit set)
static __device__ __forceinline__ uint32_t relu2bf(uint32_t x) {
    uint32_t lo = x & 0xFFFFu, hi = x >> 16;
    lo = (lo & 0x8000u) ? 0u : lo;
    hi = (hi & 0x8000u) ? 0u : hi;
    return lo | (hi << 16);
}

// ---------------------------------------------------------------------------
__global__ void diag_ws(float* __restrict__ out, float v, int n) {
    int i = blockIdx.x * 256 + threadIdx.x;
    if (i < n) out[i] = v;
}

// ---------------------------------------------------------------------------
// Merged prep (one dispatch): flags zero | h0_pack | bt_prep2 | x_prep
//                             | conv_w8 | conv_f2b(WoutB)
// Block ranges: [0,512) [512,768) [768,1280) [1280,1408) [1408,3456) [3456,3584)
// ---------------------------------------------------------------------------
struct W8 { const float* p[8]; };
struct PrepArgs {
    char* flags;                       // 2 MB -> zero
    const float* hn; bf* Hext;         // h0 pack (H2 layout)
    const float* Whh; bf* Btg2;        // Whh slice pack
    const float* tos; int* xidx; float* xval;
    W8 w8; bf* Wbf;                    // 8 attention weights -> bf16
    const float* outW; bf* WoutB;      // out weights -> bf16
};

__global__ __launch_bounds__(256) void prep_all(PrepArgs p) {
    const int blk = blockIdx.x, tid = threadIdx.x;
    if (blk < 512) {
        uint4 z = {0u, 0u, 0u, 0u};
        ((uint4*)p.flags)[blk * 256 + tid] = z;
    } else if (blk < 768) {
        int id = (blk - 512) * 256 + tid;              // 65536
        int b = id >> 9, e = id & 511;
        float v = (e < 256) ? p.hn[(size_t)b * 256 + e]
                            : p.hn[(size_t)(BB + b) * 256 + (e - 256)];
        p.Hext[((size_t)(e >> 3) * BB + b) * 8 + (e & 7)] = (bf)f2bf(v);
    } else if (blk < 1280) {
        int id = (blk - 768) * 256 + tid;              // 131072; 8 elems each
        int row = id >> 6, chunk = (id & 63) * 8;
        int cg = row >> 7, n = row & 127;
        int r = (n & 3) * 512 + cg * 32 + (n >> 2);
        const float* src = p.Whh + (size_t)r * 512 + chunk;
        ushort8 o;
#pragma unroll
        for (int i = 0; i < 8; ++i) o[i] = (bf)f2bf(src[i]);
        *(ushort8*)(p.Btg2 + (size_t)row * 512 + chunk) = o;
    } else if (blk < 1408) {
        int id = (blk - 1280) * 256 + tid;             // 32768
        int t = id >> 7, b = id & 127;
        int idx = 0; float val = 0.f;
        if (t > 0) {
            const float* row = p.tos + ((size_t)b * TT + t) * NC;
            for (int k = 0; k < NC; ++k) {
                float v = row[k];
                if (v != 0.f) { idx = k; val = v; }
            }
        }
        p.xidx[(size_t)t * BB + b] = idx;
        p.xval[(size_t)t * BB + b] = val;
    } else if (blk < 3456) {
        int idx = blk - 1408;                          // 2048 blocks
        int m = idx >> 8;
        int i = ((idx & 255) * 256 + tid) * 4;
        float4 v = *(const float4*)(p.w8.p[m] + i);
        ushort4 o = { (bf)f2bf(v.x), (bf)f2bf(v.y), (bf)f2bf(v.z), (bf)f2bf(v.w) };
        *(ushort4*)(p.Wbf + (size_t)m * 262144 + i) = o;
    } else {
        int i = ((blk - 3456) * 256 + tid) * 4;        // 131072 elems
        float4 v = *(const float4*)(p.outW + i);
        ushort4 o = { (bf)f2bf(v.x), (bf)f2bf(v.y), (bf)f2bf(v.z), (bf)f2bf(v.w) };
        *(ushort4*)(p.WoutB + i) = o;
    }
}

// ---------------------------------------------------------------------------
// shared LDS offset swizzle for the tiled worker GEMM
// ---------------------------------------------------------------------------
static __device__ __forceinline__ int lds_off(int row, int colbyte) {
    return row * 128 + (colbyte ^ ((row & 7) << 4));
}

// Worker GEMM body: C = bf16(A_f32 @ Wb^T + bias). K = 512.
// MODE 0: C[m][512] row-major.  MODE 1: V^T char  C[(b*512+n)*256+s], m=b*256+s.
// MODE 2: V^T tag  C[(b*512+n)*32+s], m=b*32+s.
template <int MODE>
static __device__ __forceinline__ void worker_gemm(
    const float* __restrict__ Af, const bf* __restrict__ Wb,
    const float* __restrict__ bias, bf* __restrict__ C,
    int bm, int bn, char* smem)
{
    bf* As = (bf*)smem;
    bf* Bs = (bf*)(smem + 16384);
    const int tid = threadIdx.x;
    const int w = tid >> 6, l = tid & 63;
    const int wr = (w >> 1) * 64, wc = (w & 1) * 64;

    f32x16 acc[2][2];
#pragma unroll
    for (int i = 0; i < 2; ++i)
#pragma unroll
        for (int j = 0; j < 2; ++j)
#pragma unroll
            for (int r = 0; r < 16; ++r) acc[i][j][r] = 0.f;

    const int srow = tid >> 3;          // 0..31
    const int scolb = (tid & 7) * 16;   // byte col
    const int scole = (tid & 7) * 8;    // elem col

    for (int k0 = 0; k0 < 512; k0 += 64) {
#pragma unroll
        for (int pass = 0; pass < 4; ++pass) {
            int row = pass * 32 + srow;
            const float* ap = Af + (size_t)(bm + row) * 512 + k0 + scole;
            float4 v0 = *(const float4*)ap;
            float4 v1 = *(const float4*)(ap + 4);
            *(uint4*)((char*)As + lds_off(row, scolb)) = pack8bf(v0, v1);
            uint4 vb = *(const uint4*)(Wb + (size_t)(bn + row) * 512 + k0 + scole);
            *(uint4*)((char*)Bs + lds_off(row, scolb)) = vb;
        }
        __syncthreads();
#pragma unroll
        for (int kt = 0; kt < 4; ++kt) {
            const int cb = kt * 32 + (l >> 5) * 16;
            short8 af[2], bfr[2];
#pragma unroll
            for (int i = 0; i < 2; ++i) {
                af[i]  = *(const short8*)((char*)As + lds_off(wr + i * 32 + (l & 31), cb));
                bfr[i] = *(const short8*)((char*)Bs + lds_off(wc + i * 32 + (l & 31), cb));
            }
#pragma unroll
            for (int i = 0; i < 2; ++i)
#pragma unroll
                for (int j = 0; j < 2; ++j)
                    acc[i][j] = __builtin_amdgcn_mfma_f32_32x32x16_bf16(af[i], bfr[j], acc[i][j], 0, 0, 0);
        }
        __syncthreads();
    }

#pragma unroll
    for (int i = 0; i < 2; ++i)
#pragma unroll
        for (int j = 0; j < 2; ++j) {
            int n = bn + wc + j * 32 + (l & 31);
            float bv = bias[n];
#pragma unroll
            for (int r = 0; r < 16; ++r) {
                int m = bm + wr + i * 32 + (r & 3) + 8 * (r >> 2) + 4 * (l >> 5);
                bf v = (bf)f2bf(acc[i][j][r] + bv);
                if constexpr (MODE == 0) {
                    C[(size_t)m * 512 + n] = v;
                } else if constexpr (MODE == 1) {
                    int b = m >> 8, s = m & 255;
                    C[((size_t)b * 512 + n) * 256 + s] = v;
                } else {
                    int b = m >> 5, s = m & 31;
                    C[((size_t)b * 512 + n) * 32 + s] = v;
                }
            }
        }
}

// ---------------------------------------------------------------------------
// Fused persistent LSTM + K/V-projection workers (V written transposed).
// ---------------------------------------------------------------------------
struct KVArgs {
    const float *Ac, *At;                  // char_enc, tag_enc (fp32)
    const bf *WcK, *WcV, *WtK, *WtV;       // bf16 weights
    const float *bcK, *bcV, *btK, *btV;    // biases
    bf *Kc, *VcT, *Kt, *VtT;               // outputs (V transposed [b][e][s])
};

__global__ __launch_bounds__(256, 1) void lstm_fused(
    bf* __restrict__ Hext,           // H2: [TT+1][64][BB][8]; [0] prefilled
    const bf* __restrict__ Btg2,     // [SC*128][512]
    const float* __restrict__ Wih,   // [2048][128]
    const float* __restrict__ bih, const float* __restrict__ bhh,
    const float* __restrict__ cn,    // [2][128][256]
    const int* __restrict__ xidx, const float* __restrict__ xval,
    char* __restrict__ flags,        // [TT][SB][16*128B], zeroed
    KVArgs kv)
{
    __shared__ __align__(16) char smem[66048];

    const int gb = blockIdx.x, tid = threadIdx.x;

    if (gb >= NWG) {
        // ---------------- worker path ----------------
        int w = gb - NWG;
        if (w < 1024) {
            worker_gemm<0>(kv.Ac, kv.WcK, kv.bcK, kv.Kc, (w >> 2) * 128, (w & 3) * 128, smem);
        } else if (w < 2048) {
            int t = w - 1024;
            worker_gemm<1>(kv.Ac, kv.WcV, kv.bcV, kv.VcT, (t >> 2) * 128, (t & 3) * 128, smem);
        } else if (w < 2176) {
            int t = w - 2048;
            worker_gemm<0>(kv.At, kv.WtK, kv.btK, kv.Kt, (t >> 2) * 128, (t & 3) * 128, smem);
        } else {
            int t = w - 2176;
            worker_gemm<2>(kv.At, kv.WtV, kv.btV, kv.VtT, (t >> 2) * 128, (t & 3) * 128, smem);
        }
        return;
    }

    // ---------------- LSTM path ----------------
    bf*    Alds   = (bf*)smem;                    // 32 KB (frag layout)
    float* gatesf = (float*)smem;                 // overlay: [32][132] fp32
    bf*    wihtp  = (bf*)(smem + 32768);          // [128][128]
    float* biass  = (float*)(smem + 65536);       // [128]

    const int g = gb;
    const int bh = g >> 4, cg = g & 15;

    // ---- prologue: WihT slice + bias ----
    for (int x = tid; x < 128 * NC; x += 256) {   // x = n*128 + k
        int n = x >> 7, k = x & 127;
        int r = (n & 3) * 512 + cg * 32 + (n >> 2);
        wihtp[k * 128 + n] = (bf)f2bf(Wih[(size_t)r * NC + k]);
    }
    if (tid < 128) {
        int r = (tid & 3) * 512 + cg * 32 + (tid >> 2);
        biass[tid] = bih[r] + bhh[r];
    }

    const int b_loc = tid >> 3, u = tid & 7;
    const int b_glob = bh * 32 + b_loc;
    float creg[4];
    {
        int j0 = cg * 32 + u * 4;
        const float* csrc = (cg < 8) ? (cn + (size_t)b_glob * 256 + j0)
                                     : (cn + (size_t)(BB + b_glob) * 256 + (j0 - 256));
#pragma unroll
        for (int i = 0; i < 4; ++i) creg[i] = csrc[i];
    }

    const int wv = tid >> 6, l = tid & 63;

    // B preload into registers: 32 k-steps x short8 = 128 VGPR, kept all run
    short8 breg[32];
    {
        const bf* bsrc = Btg2 + ((size_t)(cg * 128 + wv * 32 + (l & 31)) * 512)
                       + (l >> 5) * 8;
#pragma unroll
        for (int kt = 0; kt < 32; ++kt) breg[kt] = *(const short8*)(bsrc + kt * 16);
    }
    __syncthreads();

    const int sb = tid & 31, sg0 = tid >> 5;
    const int dst_lane = sb | ((sg0 & 1) << 5);
    bf* dstbase = Alds + (size_t)(sg0 >> 1) * 512 + dst_lane * 8;   // + i*2048

    u64* Hw = (u64*)Hext;
    const size_t SLABB = (size_t)BB * EE * 2;      // bytes per t-slab
    const size_t SLAB64 = (size_t)BB * EE / 4;     // u64 per t-slab
    const size_t hst_off = (size_t)(cg * 4 + (u >> 1)) * 256 + b_glob * 2 + (u & 1);
    const bf* ards = Alds + l * 8;

    for (int t = 0; t < TT; ++t) {
        // ---- stage A: 8 batched bypass dwordx4 loads -> LDS (frag layout) ----
        const char* At = (const char*)Hext + (size_t)t * SLABB
                       + (size_t)sg0 * 2048 + (size_t)(bh * 32 + sb) * 16;
        uint4 areg[8];
#pragma unroll
        for (int i = 0; i < 8; ++i) {
            asm volatile("global_load_dwordx4 %0, %1, off sc0 sc1"
                         : "=v"(areg[i]) : "v"(At + (size_t)i * 16384));
        }
        float xv = xval[(size_t)t * BB + b_glob];
        int   xi = xidx[(size_t)t * BB + b_glob];
        asm volatile("s_waitcnt vmcnt(0)" ::: "memory");
        __builtin_amdgcn_sched_barrier(0);
#pragma unroll
        for (int i = 0; i < 8; ++i)
            *(uint4*)(dstbase + (size_t)i * 2048) = areg[i];
        __syncthreads();

        // ---- gates tile: 32 rows x 32 cols per wave, K=512 ----
        f32x16 acc0, acc1;
#pragma unroll
        for (int i = 0; i < 16; ++i) { acc0[i] = 0.f; acc1[i] = 0.f; }
#pragma unroll
        for (int kt = 0; kt < 32; kt += 2) {
            short8 a0 = *(const short8*)(ards + (size_t)kt * 512);
            short8 a1 = *(const short8*)(ards + (size_t)(kt + 1) * 512);
            acc0 = __builtin_amdgcn_mfma_f32_32x32x16_bf16(a0, breg[kt], acc0, 0, 0, 0);
            acc1 = __builtin_amdgcn_mfma_f32_32x32x16_bf16(a1, breg[kt + 1], acc1, 0, 0, 0);
        }
        __syncthreads();   // Alds reads complete before gates overlay write
#pragma unroll
        for (int r = 0; r < 16; ++r) {
            int m = (r & 3) + 8 * (r >> 2) + 4 * (l >> 5);   // verified C/D map
            gatesf[m * 132 + wv * 32 + (l & 31)] = acc0[r] + acc1[r];
        }
        __syncthreads();

        // ---- nonlinearity ----
        {
            union { ushort4 v; u64 uu; } hout;
#pragma unroll
            for (int i = 0; i < 4; ++i) {
                int nb = (u * 4 + i) * 4;          // gate-col base (q=0..3)
                float4 ga  = *(const float4*)&gatesf[b_loc * 132 + nb];
                float4 bb4 = *(const float4*)&biass[nb];
                ushort4 xw = *(const ushort4*)&wihtp[xi * 128 + nb];
                float a0 = ga.x + bb4.x + xv * bfu(xw.x);   // i
                float a1 = ga.y + bb4.y + xv * bfu(xw.y);   // f
                float a2 = ga.z + bb4.z + xv * bfu(xw.z);   // g
                float a3 = ga.w + bb4.w + xv * bfu(xw.w);   // o
                float ig = sigmoidf_(a0);
                float fg = sigmoidf_(a1);
                float gg = tanhf(a2);
                float og = sigmoidf_(a3);
                creg[i] = fg * creg[i] + ig * gg;
                float hnew = og * tanhf(creg[i]);
                hout.v[i] = (bf)f2bf(hnew);
            }
            __hip_atomic_store(Hw + (size_t)(t + 1) * SLAB64 + hst_off, hout.uu,
                               __ATOMIC_RELAXED, __HIP_MEMORY_SCOPE_AGENT);
        }

        if (t + 1 < TT) {
            asm volatile("s_waitcnt vmcnt(0)" ::: "memory");   // h stores drained
            __syncthreads();
            char* fb = flags + (size_t)(t + 1) * (SB * 2048) + (size_t)bh * 2048;
            if (tid == 0)
                __hip_atomic_store((int*)(fb + (size_t)cg * 128), 1,
                                   __ATOMIC_RELAXED, __HIP_MEMORY_SCOPE_SYSTEM);
            if (tid < 64) {
                const int* fp = (const int*)(fb + (size_t)(tid & 15) * 128);
                while (true) {
                    int v = __hip_atomic_load(fp, __ATOMIC_RELAXED,
                                              __HIP_MEMORY_SCOPE_SYSTEM);
                    if (__all(v != 0)) break;
                    __builtin_amdgcn_s_sleep(1);
                }
            }
            asm volatile("" ::: "memory");
            __syncthreads();
        }
    }
}

// ---------------------------------------------------------------------------
// Merged fused MFMA attention (both sides, one dispatch), overlay LDS 66.5KB
// -> 2 blocks/CU. Per (b, 32-t tile): Hstage + Qproj + QK^T + softmax + PV + Wo.
// Region overlay (verified hazard-free):
//   L = [0,33280): Qs (Q, later ctx); Ps aliases L (written after Q dead)
//   U = [33280,66560): Hs (H stage, dead after ph1); scs (scores) overwrites
//       it in ph2; occs aliases U after scs dead.
// ---------------------------------------------------------------------------
template <int S>
static __device__ void attn_side(
    const bf* __restrict__ Hext,    // H2 base; slab t+1 = h_t
    const bf* __restrict__ Wq, const float* __restrict__ bq,
    const bf* __restrict__ Km,      // [BB*S][512]
    const bf* __restrict__ VT,      // [BB][512][S]
    const bf* __restrict__ Wo, const float* __restrict__ bo,
    bf* __restrict__ occ,           // [TT*BB][512]
    int t0, int b, int tid, char* smem)
{
    constexpr int SP = S + 4;     // scs pad (fp32 elems)
    constexpr int PP = S + 8;     // Ps pad (bf elems)
    bf*    Qs   = (bf*)smem;                    // [32][520]
    float* scs  = (float*)(smem + 33280);       // [32][SP]
    bf*    Ps   = (bf*)smem;                    // aliases Qs
    bf*    occs = (bf*)(smem + 33280);          // aliases scs
    char*  Hs   = smem + 33280;                 // H stage (dead before scs)

    const float QSCALE = 0.044194173824159216f;
    const int wv = tid >> 6, l = tid & 63;
    const int lm = l & 31, lh = l >> 5;

    // ---- ph0: stage H tile (t0+1..t0+32, 64 grps) for batch b -> LDS ----
    // Hs layout: [tl][grp^(tl&7)] 16B chunks (XOR spreads banks; <=4-way)
    for (int x = tid; x < 2048; x += 256) {
        int tl = x >> 6, grp = x & 63;
        uint4 v = *(const uint4*)(Hext + (((size_t)(t0 + tl + 1) * 64 + grp) * BB + b) * 8);
        *(uint4*)(Hs + tl * 1024 + ((grp ^ (tl & 7)) << 4)) = v;
    }
    __syncthreads();

    // ---- ph1: Q = (h @ Wq^T + bq)*QSCALE  (A-frags from LDS, 4x dedupe) ----
    {
        f32x16 qa[4];
#pragma unroll
        for (int nt = 0; nt < 4; ++nt)
#pragma unroll
            for (int r = 0; r < 16; ++r) qa[nt][r] = 0.f;
#pragma unroll 4
        for (int kt = 0; kt < 32; ++kt) {
            short8 a = *(const short8*)(Hs + lm * 1024 + (((kt * 2 + lh) ^ (lm & 7)) << 4));
#pragma unroll
            for (int nt = 0; nt < 4; ++nt) {
                int n = wv * 128 + nt * 32 + lm;
                short8 w = *(const short8*)(Wq + (size_t)n * 512 + kt * 16 + lh * 8);
                qa[nt] = __builtin_amdgcn_mfma_f32_32x32x16_bf16(a, w, qa[nt], 0, 0, 0);
            }
        }
#pragma unroll
        for (int nt = 0; nt < 4; ++nt) {
            int n = wv * 128 + nt * 32 + lm;
            float bv = bq[n];
#pragma unroll
            for (int r = 0; r < 16; ++r) {
                int m = (r & 3) + 8 * (r >> 2) + 4 * lh;
                Qs[m * 520 + n] = (bf)f2bf((qa[nt][r] + bv) * QSCALE);
            }
        }
    }
    __syncthreads();   // H reads done; U region free for scs

    // ---- ph2: scores = Q @ K^T ----
    {
        constexpr int NJ = (S == 256) ? 2 : 1;
        f32x16 sa[NJ];
#pragma unroll
        for (int j = 0; j < NJ; ++j)
#pragma unroll
            for (int r = 0; r < 16; ++r) sa[j][r] = 0.f;
#pragma unroll 4
        for (int kt = 0; kt < 32; ++kt) {
            short8 a = *(const short8*)&Qs[lm * 520 + kt * 16 + lh * 8];
#pragma unroll
            for (int j = 0; j < NJ; ++j) {
                int s = ((S == 256) ? (wv * 64 + j * 32) : 0) + lm;
                short8 k8 = *(const short8*)(Km + ((size_t)b * S + s) * 512 + kt * 16 + lh * 8);
                sa[j] = __builtin_amdgcn_mfma_f32_32x32x16_bf16(a, k8, sa[j], 0, 0, 0);
            }
        }
#pragma unroll
        for (int j = 0; j < NJ; ++j) {
            int s = ((S == 256) ? (wv * 64 + j * 32) : 0) + lm;
#pragma unroll
            for (int r = 0; r < 16; ++r) {
                int m = (r & 3) + 8 * (r >> 2) + 4 * lh;
                scs[m * SP + s] = sa[j][r];     // S==32: waves write same values (benign)
            }
        }
    }
    __syncthreads();

    // ---- ph3: softmax (8 threads/row); P(bf16) -> Ps (aliases dead Q) ----
    {
        int r = tid >> 3, lg = tid & 7;
        float mx = -1e30f;
        for (int c = lg; c < S; c += 8) mx = fmaxf(mx, scs[r * SP + c]);
#pragma unroll
        for (int d = 1; d < 8; d <<= 1) mx = fmaxf(mx, __shfl_xor(mx, d));
        float sum = 0.f;
        for (int c = lg; c < S; c += 8) {
            float e = expf(scs[r * SP + c] - mx);
            scs[r * SP + c] = e;
            sum += e;
        }
#pragma unroll
        for (int d = 1; d < 8; d <<= 1) sum += __shfl_xor(sum, d);
        float inv = 1.f / sum;
        for (int c = lg; c < S; c += 8) Ps[r * PP + c] = (bf)f2bf(scs[r * SP + c] * inv);
    }
    __syncthreads();

    // ---- ph4: ctx = P @ V ----
    {
        f32x16 ca[4];
#pragma unroll
        for (int nt = 0; nt < 4; ++nt)
#pragma unroll
            for (int r = 0; r < 16; ++r) ca[nt][r] = 0.f;
#pragma unroll
        for (int kt = 0; kt < S / 16; ++kt) {
            short8 a = *(const short8*)&Ps[lm * PP + kt * 16 + lh * 8];
#pragma unroll
            for (int nt = 0; nt < 4; ++nt) {
                int n = wv * 128 + nt * 32 + lm;
                short8 v8 = *(const short8*)(VT + ((size_t)b * 512 + n) * S + kt * 16 + lh * 8);
                ca[nt] = __builtin_amdgcn_mfma_f32_32x32x16_bf16(a, v8, ca[nt], 0, 0, 0);
            }
        }
        __syncthreads();   // all P reads done -> safe to overwrite L region
#pragma unroll
        for (int nt = 0; nt < 4; ++nt) {
            int n = wv * 128 + nt * 32 + lm;
#pragma unroll
            for (int r = 0; r < 16; ++r) {
                int m = (r & 3) + 8 * (r >> 2) + 4 * lh;
                Qs[m * 520 + n] = (bf)f2bf(ca[nt][r]);
            }
        }
    }
    __syncthreads();

    // ---- ph5: occ = ctx @ Wo^T + bo ; stage in LDS, coalesced store ----
    {
        f32x16 oa[4];
#pragma unroll
        for (int nt = 0; nt < 4; ++nt)
#pragma unroll
            for (int r = 0; r < 16; ++r) oa[nt][r] = 0.f;
#pragma unroll 4
        for (int kt = 0; kt < 32; ++kt) {
            short8 a = *(const short8*)&Qs[lm * 520 + kt * 16 + lh * 8];
#pragma unroll
            for (int nt = 0; nt < 4; ++nt) {
                int n = wv * 128 + nt * 32 + lm;
                short8 w = *(const short8*)(Wo + (size_t)n * 512 + kt * 16 + lh * 8);
                oa[nt] = __builtin_amdgcn_mfma_f32_32x32x16_bf16(a, w, oa[nt], 0, 0, 0);
            }
        }
#pragma unroll
        for (int nt = 0; nt < 4; ++nt) {
            int n = wv * 128 + nt * 32 + lm;
            float bv = bo[n];
#pragma unroll
            for (int r = 0; r < 16; ++r) {
                int m = (r & 3) + 8 * (r >> 2) + 4 * lh;
                occs[m * 520 + n] = (bf)f2bf(oa[nt][r] + bv);
            }
        }
        __syncthreads();
        int row = tid >> 3, c0 = (tid & 7) * 64;
        const bf* src = occs + row * 520 + c0;
        bf* dst = occ + ((size_t)(t0 + row) * BB + b) * 512 + c0;
#pragma unroll
        for (int k = 0; k < 8; ++k)
            *(uint4*)(dst + k * 8) = *(const uint4*)(src + k * 8);
    }
}

struct AttnArgs {
    const bf* Hext;
    const bf *WcQ, *WcO, *WtQ, *WtO;
    const float *bcq, *bco, *btq, *bto;
    const bf *Kc, *VcT, *Kt, *VtT;
    bf *Occ, *Oct;
};

__global__ __launch_bounds__(256, 2) void attn_all(AttnArgs a) {
    __shared__ __align__(16) char smem[66560];
    const int t0 = blockIdx.x * 32, b = blockIdx.y, tid = threadIdx.x;
    if (blockIdx.z == 0)
        attn_side<256>(a.Hext, a.WcQ, a.bcq, a.Kc, a.VcT, a.WcO, a.bco, a.Occ,
                       t0, b, tid, smem);
    else
        attn_side<32>(a.Hext, a.WtQ, a.btq, a.Kt, a.VtT, a.WtO, a.bto, a.Oct,
                      t0, b, tid, smem);
}

// ---------------------------------------------------------------------------
// Output projection (MFMA): out[b][t][:] = relu(Occ[m]) @ Wo[:, :512]^T
//   + relu(Oct[m]) @ Wo[:, 512:]^T + bias,  m = t*BB + b. N = 128.
// ---------------------------------------------------------------------------
__global__ __launch_bounds__(256) void gemm_out(
    const bf* __restrict__ A1, const bf* __restrict__ A2,
    const bf* __restrict__ Wo,      // [128][1024] bf16
    const float* __restrict__ bias, float* __restrict__ out)
{
    __shared__ __align__(16) bf As[128 * 64];
    __shared__ __align__(16) bf Bs[128 * 64];
    const int tid = threadIdx.x;
    const int bm = blockIdx.x * 128;
    const int w = tid >> 6, l = tid & 63;
    const int wr = (w >> 1) * 64, wc = (w & 1) * 64;

    f32x16 acc[2][2];
#pragma unroll
    for (int i = 0; i < 2; ++i)
#pragma unroll
        for (int j = 0; j < 2; ++j)
#pragma unroll
            for (int r = 0; r < 16; ++r) acc[i][j][r] = 0.f;

    const int srow = tid >> 3;
    const int scolb = (tid & 7) * 16;
    const int scole = (tid & 7) * 8;

    for (int k0 = 0; k0 < 1024; k0 += 64) {
        const bf* Asrc = (k0 < 512) ? A1 : A2;
        const int kk = k0 & 511;
#pragma unroll
        for (int pass = 0; pass < 4; ++pass) {
            int row = pass * 32 + srow;
            uint4 va = *(const uint4*)(Asrc + (size_t)(bm + row) * 512 + kk + scole);
            va.x = relu2bf(va.x); va.y = relu2bf(va.y);
            va.z = relu2bf(va.z); va.w = relu2bf(va.w);
            *(uint4*)((char*)As + lds_off(row, scolb)) = va;
            uint4 vb = *(const uint4*)(Wo + (size_t)row * 1024 + k0 + scole);
            *(uint4*)((char*)Bs + lds_off(row, scolb)) = vb;
        }
        __syncthreads();
#pragma unroll
        for (int kt = 0; kt < 4; ++kt) {
            const int cb = kt * 32 + (l >> 5) * 16;
            short8 af[2], bfr[2];
#pragma unroll
            for (int i = 0; i < 2; ++i) {
                af[i]  = *(const short8*)((char*)As + lds_off(wr + i * 32 + (l & 31), cb));
                bfr[i] = *(const short8*)((char*)Bs + lds_off(wc + i * 32 + (l & 31), cb));
            }
#pragma unroll
            for (int i = 0; i < 2; ++i)
#pragma unroll
                for (int j = 0; j < 2; ++j)
                    acc[i][j] = __builtin_amdgcn_mfma_f32_32x32x16_bf16(af[i], bfr[j], acc[i][j], 0, 0, 0);
        }
        __syncthreads();
    }

    // epilogue: remap rows (t,b)->(b,t), fp32 store
#pragma unroll
    for (int i = 0; i < 2; ++i)
#pragma unroll
        for (int j = 0; j < 2; ++j) {
            int n = wc + j * 32 + (l & 31);
            float bv = bias[n];
#pragma unroll
            for (int r = 0; r < 16; ++r) {
                int m = bm + wr + i * 32 + (r & 3) + 8 * (r >> 2) + 4 * (l >> 5);
                int tt = m >> 7, bb_ = m & 127;
                out[((size_t)bb_ * TT + tt) * NC + n] = acc[i][j][r] + bv;
            }
        }
}

// ---------------------------------------------------------------------------
extern "C" void kernel_launch(void* const* d_in, const int* in_sizes, int n_in,
                              void* d_out, int out_size, void* d_ws, size_t ws_size,
                              hipStream_t stream) {
    const float* char_enc = (const float*)d_in[0];
    const float* char_hn  = (const float*)d_in[1];
    const float* char_cn  = (const float*)d_in[2];
    const float* tag_enc  = (const float*)d_in[3];
    const float* tos      = (const float*)d_in[4];
    const float* Wih = (const float*)d_in[5];
    const float* Whh = (const float*)d_in[6];
    const float* bih = (const float*)d_in[7];
    const float* bhh = (const float*)d_in[8];
    const float* caWq = (const float*)d_in[9],  *caWk = (const float*)d_in[10], *caWv = (const float*)d_in[11];
    const float* cabq = (const float*)d_in[12], *cabk = (const float*)d_in[13], *cabv = (const float*)d_in[14];
    const float* caWo = (const float*)d_in[15], *cabo = (const float*)d_in[16];
    const float* taWq = (const float*)d_in[17], *taWk = (const float*)d_in[18], *taWv = (const float*)d_in[19];
    const float* tabq = (const float*)d_in[20], *tabk = (const float*)d_in[21], *tabv = (const float*)d_in[22];
    const float* taWo = (const float*)d_in[23], *tabo = (const float*)d_in[24];
    const float* outW = (const float*)d_in[25], *outb = (const float*)d_in[26];
    float* out = (float*)d_out;

    const size_t SZ  = (size_t)TT * BB * EE;       // 16,777,216 elements
    const size_t SZT = (size_t)BB * STAG * EE;     //  2,097,152 elements
    const size_t SLAB = (size_t)BB * EE;           // one t-slab of H2
    const size_t HEXT = SZ + SLAB;                 // (TT+1) slabs
    const size_t FLAGB = (size_t)TT * SB * 2048;   // 2 MB: per-step group flags

    const size_t NEED = FLAGB + HEXT * 2 + 4 * SZ * 2 + 2 * SZT * 2
                      + (size_t)SC * 128 * EE * 2 + (size_t)TT * BB * 8
                      + (8 * 262144 + 131072) * 2;
    if (ws_size < NEED) {
        diag_ws<<<dim3((out_size + 255) / 256), dim3(256), 0, stream>>>(
            out, (float)((double)ws_size / 1048576.0), out_size);
        return;
    }

    char* w = (char*)d_ws;
    char* flags = w;             w += FLAGB;
    bf* Hext = (bf*)w;           w += HEXT * 2;    // H2 layout
    bf* Kc = (bf*)w;             w += SZ * 2;      // K char [b*256+s][512]
    bf* VcT = (bf*)w;            w += SZ * 2;      // V char transposed [b][512][256]
    bf* Occ = (bf*)w;            w += SZ * 2;      // occ output of attn_c
    bf* Oct = (bf*)w;            w += SZ * 2;      // oct output of attn_t
    bf* Kt = (bf*)w;             w += SZT * 2;
    bf* VtT = (bf*)w;            w += SZT * 2;     // [b][512][32]
    bf* Btg2 = (bf*)w;           w += (size_t)SC * 128 * EE * 2;
    int* xidx = (int*)w;         w += (size_t)TT * BB * 4;
    float* xval = (float*)w;     w += (size_t)TT * BB * 4;
    bf* Wbf = (bf*)w;            w += 8 * 262144 * 2;
    bf* WoutB = (bf*)w;          w += 131072 * 2;

    bf* WbcaK = Wbf + 0 * 262144; bf* WbcaV = Wbf + 1 * 262144;
    bf* WbcaQ = Wbf + 2 * 262144; bf* WbcaO = Wbf + 3 * 262144;
    bf* WbtaK = Wbf + 4 * 262144; bf* WbtaV = Wbf + 5 * 262144;
    bf* WbtaQ = Wbf + 6 * 262144; bf* WbtaO = Wbf + 7 * 262144;

    // ---- merged prep (one dispatch) ----
    PrepArgs pp;
    pp.flags = flags;
    pp.hn = char_hn; pp.Hext = Hext;
    pp.Whh = Whh; pp.Btg2 = Btg2;
    pp.tos = tos; pp.xidx = xidx; pp.xval = xval;
    pp.w8.p[0] = caWk; pp.w8.p[1] = caWv; pp.w8.p[2] = caWq; pp.w8.p[3] = caWo;
    pp.w8.p[4] = taWk; pp.w8.p[5] = taWv; pp.w8.p[6] = taWq; pp.w8.p[7] = taWo;
    pp.Wbf = Wbf;
    pp.outW = outW; pp.WoutB = WoutB;
    prep_all<<<dim3(3584), dim3(256), 0, stream>>>(pp);

    // ---- fused: persistent LSTM + K/V projection workers (V transposed) ----
    KVArgs kv;
    kv.Ac = char_enc; kv.At = tag_enc;
    kv.WcK = WbcaK; kv.WcV = WbcaV; kv.WtK = WbtaK; kv.WtV = WbtaV;
    kv.bcK = cabk; kv.bcV = cabv; kv.btK = tabk; kv.btV = tabv;
    kv.Kc = Kc; kv.VcT = VcT; kv.Kt = Kt; kv.VtT = VtT;
    lstm_fused<<<dim3(NWG + NKV), dim3(256), 0, stream>>>(
        Hext, Btg2, Wih, bih, bhh, char_cn, xidx, xval, flags, kv);

    // ---- merged fused MFMA attention (both sides, 2 blocks/CU) ----
    AttnArgs aa;
    aa.Hext = Hext;
    aa.WcQ = WbcaQ; aa.WcO = WbcaO; aa.WtQ = WbtaQ; aa.WtO = WbtaO;
    aa.bcq = cabq; aa.bco = cabo; aa.btq = tabq; aa.bto = tabo;
    aa.Kc = Kc; aa.VcT = VcT; aa.Kt = Kt; aa.VtT = VtT;
    aa.Occ = Occ; aa.Oct = Oct;
    attn_all<<<dim3(TT / 32, BB, 2), dim3(256), 0, stream>>>(aa);

    // ---- output projection (MFMA, fused both halves + relu + remap) ----
    gemm_out<<<dim3(256), dim3(256), 0, stream>>>(Occ, Oct, WoutB, outb, out);
}